// Round 1
// baseline (288.553 us; speedup 1.0000x reference)
//
#include <hip/hip_runtime.h>

#define NN 100000
#define NE 1600000
#define NG 64
#define CAP 64      // per-node bucket capacity; deg ~ Poisson(16)
#define NPB 80      // nodes per block in h2pool (100000/80 = 1250 blocks)
#define NBUCK 391   // ceil(NN/256): coarse buckets of 256 nodes
#define NBLK 391    // sort blocks; 391*4096 >= 1.6M
#define EPB 4096    // edges per sort block
#define BCAP 4608   // bucket segment capacity (mean 4093 + ~8 sigma)
#define NSLOT 32    // pooled2 slots per graph (blocks/graph span <= 22)

// fast a/b: raw v_rcp_f32 (~1 ulp on gfx950) — Newton step dropped (measured
// absmax margin is ~5000x; 1-ulp rcp shifts output by <=1e-7 relative)
__device__ __forceinline__ float fast_div(float n, float d) {
  return n * __builtin_amdgcn_rcpf(d);
}
__device__ __forceinline__ float silu_f(float x) {
  return fast_div(x, 1.0f + __expf(-x));
}

// ---- Build A: count + atomic-reserve + scatter, in ONE kernel. ----
__global__ void k_scatter(const int* __restrict__ row, const int* __restrict__ col,
                          const float* __restrict__ ew, int* __restrict__ gcnt,
                          int2* __restrict__ sorted, float* __restrict__ pooled2) {
  __shared__ int h[NBUCK];
  __shared__ int base[NBUCK];
  __shared__ int curh[NBUCK];
  int tid = threadIdx.x;  // 512
  for (int i = tid; i < NBUCK; i += 512) { h[i] = 0; curh[i] = 0; }
  for (int i = blockIdx.x * 512 + tid; i < NG * NSLOT * 200; i += NBLK * 512)
    pooled2[i] = 0.0f;
  __syncthreads();
  int s = blockIdx.x * EPB;
  for (int i = 0; i < EPB / 2048; ++i) {
    int e = s + i * 2048 + tid * 4;
    if (e + 3 < NE) {
      int4 c4 = *(const int4*)(col + e);
      atomicAdd(&h[c4.x >> 8], 1);
      atomicAdd(&h[c4.y >> 8], 1);
      atomicAdd(&h[c4.z >> 8], 1);
      atomicAdd(&h[c4.w >> 8], 1);
    } else {
      for (int j = 0; j < 4; ++j) {
        int ee = e + j;
        if (ee < NE) atomicAdd(&h[col[ee] >> 8], 1);
      }
    }
  }
  __syncthreads();
  for (int i = tid; i < NBUCK; i += 512)
    base[i] = (h[i] > 0) ? atomicAdd(&gcnt[i * 16], h[i]) : 0;
  __syncthreads();
  for (int i = 0; i < EPB / 2048; ++i) {
    int e = s + i * 2048 + tid * 4;
    if (e + 3 < NE) {
      int4 r4 = *(const int4*)(row + e);
      int4 c4 = *(const int4*)(col + e);
      float4 w4 = *(const float4*)(ew + e);
#define SC1(cc, rr, ww) { \
  int b = (cc) >> 8; \
  int p = base[b] + atomicAdd(&curh[b], 1); \
  if (p < BCAP) \
    sorted[(size_t)b * BCAP + p] = \
        make_int2((rr) | (((cc) & 255) << 17), __float_as_int(ww)); }
      SC1(c4.x, r4.x, w4.x)
      SC1(c4.y, r4.y, w4.y)
      SC1(c4.z, r4.z, w4.z)
      SC1(c4.w, r4.w, w4.w)
    } else {
      for (int j = 0; j < 4; ++j) {
        int ee = e + j;
        if (ee < NE) { SC1(col[ee], row[ee], ew[ee]) }
      }
#undef SC1
    }
  }
}

// ---- Build B: per-bucket node grouping into buck/cur + y4 = (dinv*x, dinv) ----
__global__ void k_group(const int* __restrict__ gcnt, const int2* __restrict__ sorted,
                        int* __restrict__ cur, int2* __restrict__ buck,
                        const float* __restrict__ x, float4* __restrict__ y4) {
  __shared__ int cnt[256];
  __shared__ float wsum[256];
  int b = blockIdx.x, tid = threadIdx.x;
  int n = min(gcnt[b * 16], BCAP);
  size_t s = (size_t)b * BCAP;
  if (tid < 256) { cnt[tid] = 0; wsum[tid] = 0.0f; }
  __syncthreads();
  for (int i = tid; i < n; i += 512) {
    int2 pk = sorted[s + i];
    int node = (pk.x >> 17) & 255;
    int rank = atomicAdd(&cnt[node], 1);
    atomicAdd(&wsum[node], __int_as_float(pk.y));
    if (rank < CAP)
      buck[(((size_t)b * 256 + node) << 6) + rank] = make_int2(pk.x & 0x1FFFF, pk.y);
  }
  __syncthreads();
  if (tid < 256) {
    int gnode = b * 256 + tid;
    if (gnode < NN) {
      cur[gnode] = cnt[tid];
      float di = rsqrtf(wsum[tid] + 1.0f);  // +1 = self-loop weight
      y4[gnode] = make_float4(di * x[3 * gnode + 0], di * x[3 * gnode + 1],
                              di * x[3 * gnode + 2], di);
    }
  }
}

// ---- layer-1 aggregation: 4 nodes per wave; writes a1d = (a1, dinv) float4. ----
__global__ void k_agg1(const int* __restrict__ cur, const int2* __restrict__ buck,
                       const float4* __restrict__ y4, float4* __restrict__ a1d) {
  int wave = threadIdx.x >> 6, lane = threadIdx.x & 63;
  int sub = lane >> 4, rank = lane & 15;
  int cbase = blockIdx.x * 16 + wave * 4;   // NN = 6250*16 exactly
  int c = cbase + sub;
  int cnt = min(cur[c], CAP);
  float s0 = 0.0f, s1 = 0.0f, s2 = 0.0f;
  for (int p = rank; p < cnt; p += 16) {
    int2 pk = buck[((size_t)c << 6) + p];
    float ww = __int_as_float(pk.y);
    float4 v = y4[pk.x];
    s0 += ww * v.x;
    s1 += ww * v.y;
    s2 += ww * v.z;
  }
  for (int s = 8; s; s >>= 1) {
    s0 += __shfl_down(s0, s, 16);
    s1 += __shfl_down(s1, s, 16);
    s2 += __shfl_down(s2, s, 16);
  }
  if (rank == 0) {
    float4 vc = y4[c];
    float dc = vc.w;
    a1d[c] = make_float4((s0 + vc.x) * dc, (s1 + vc.y) * dc, (s2 + vc.z) * dc, dc);
  }
}

// ---- layer-2 aggregation with ON-THE-FLY z1' recompute (fast silu, x2 unroll). ----
__global__ void k_agg2r(const float4* __restrict__ a1d, const int* __restrict__ cur,
                        const int2* __restrict__ buck, const float* __restrict__ W1,
                        const float* __restrict__ b1, float* __restrict__ a2) {
  int wave = threadIdx.x >> 6;
  int lane = threadIdx.x & 63;
  int c = blockIdx.x * 4 + wave;
  if (c >= NN) return;
  int grp = lane >> 5;
  int li = lane & 31;
  bool act = li < 25;
  float4 w0, w1, w2, bb;
  if (act) {
    w0 = ((const float4*)W1)[li];          // W1[0][4li..4li+3]
    w1 = ((const float4*)(W1 + 100))[li];  // W1[1][...]
    w2 = ((const float4*)(W1 + 200))[li];  // W1[2][...]
    bb = ((const float4*)b1)[li];
  }
  float4 ac = a1d[c];
  float dc = ac.w;
  float4 acc = make_float4(0.f, 0.f, 0.f, 0.f);
#define ZACC(av, cf) { \
  float m = (cf) * (av).w; \
  float vx = bb.x + (av).x * w0.x + (av).y * w1.x + (av).z * w2.x; \
  float vy = bb.y + (av).x * w0.y + (av).y * w1.y + (av).z * w2.y; \
  float vz = bb.z + (av).x * w0.z + (av).y * w1.z + (av).z * w2.z; \
  float vw = bb.w + (av).x * w0.w + (av).y * w1.w + (av).z * w2.w; \
  acc.x += m * silu_f(vx); \
  acc.y += m * silu_f(vy); \
  acc.z += m * silu_f(vz); \
  acc.w += m * silu_f(vw); }
  if (grp == 0 && act) ZACC(ac, dc)  // self term: coef = dc, dn = ac.w
  int cnt = min(cur[c], CAP);
  int2 pk = make_int2(0, 0);
  if (lane < cnt) pk = buck[((size_t)c << 6) + lane];
  int p = 0;
  for (; p + 4 <= cnt; p += 4) {  // 4 edges: each group takes p+grp and p+2+grp
    int rva = __shfl(pk.x, p + grp, 64);
    float cfa = __int_as_float(__shfl(pk.y, p + grp, 64)) * dc;
    int rvb = __shfl(pk.x, p + 2 + grp, 64);
    float cfb = __int_as_float(__shfl(pk.y, p + 2 + grp, 64)) * dc;
    float4 ava = a1d[rva];  // independent 16B loads, both in flight
    float4 avb = a1d[rvb];
    if (act) { ZACC(ava, cfa) ZACC(avb, cfb) }
  }
  for (; p + 2 <= cnt; p += 2) {  // pair: group 0 -> edge p, group 1 -> edge p+1
    int rv = __shfl(pk.x, p + grp, 64);
    float cf = __int_as_float(__shfl(pk.y, p + grp, 64)) * dc;
    float4 av = a1d[rv];
    if (act) ZACC(av, cf)
  }
  if (p < cnt) {  // single tail: group 0 only
    int rv = __shfl(pk.x, p, 64);
    float cf = __int_as_float(__shfl(pk.y, p, 64)) * dc;
    float4 av = a1d[rv];
    if (grp == 0 && act) ZACC(av, cf)
  }
#undef ZACC
  // combine group B (lanes 32-56) into group A (lanes 0-24)
  acc.x += __shfl(acc.x, lane + 32, 64);
  acc.y += __shfl(acc.y, lane + 32, 64);
  acc.z += __shfl(acc.z, lane + 32, 64);
  acc.w += __shfl(acc.w, lane + 32, 64);
  if (grp == 0 && act) ((float4*)a2)[(size_t)c * 25 + li] = acc;
}

// ---- fused z2 = silu(a2@W2+b2) + pool partials; NO global atomics. ----
__global__ void k_h2pool(const float* __restrict__ a2, const float* __restrict__ W2,
                         const float* __restrict__ b2, const int* __restrict__ batch,
                         float* __restrict__ pooled2) {
  __shared__ float zst[100 * 84];   // [k][node], 80 padded to 84 (33.6 KB)
  __shared__ float part[6 * 200];   // per-graph partials (4.8 KB)
  __shared__ int bsm[NPB];
  int tid = threadIdx.x;
  int nb = blockIdx.x * NPB;
  int slot = blockIdx.x & (NSLOT - 1);
  const float4* a2v = (const float4*)(a2 + (size_t)nb * 100);
  for (int i = tid; i < NPB * 25; i += 256) {
    int n = i / 25, c = i % 25;
    float4 v = a2v[i];
    zst[(4 * c + 0) * 84 + n] = v.x;
    zst[(4 * c + 1) * 84 + n] = v.y;
    zst[(4 * c + 2) * 84 + n] = v.z;
    zst[(4 * c + 3) * 84 + n] = v.w;
  }
  if (tid < NPB) bsm[tid] = batch[nb + tid];
  for (int i = tid; i < 1200; i += 256) part[i] = 0.0f;
  __syncthreads();
  int gmin = bsm[0];
  int ngr = bsm[NPB - 1] - gmin + 1;  // batch sorted
  int q = tid % 25;  // col octet: cols 8q..8q+7
  int r = tid / 25;  // node octet: nodes 8r..8r+7
  if (r < 10) {
    int n0 = r * 8;
    float4 acc0[8], acc1[8];
#pragma unroll
    for (int i = 0; i < 8; ++i) {
      acc0[i] = make_float4(0.f, 0.f, 0.f, 0.f);
      acc1[i] = make_float4(0.f, 0.f, 0.f, 0.f);
    }
    const float4* W2v = (const float4*)W2;
#pragma unroll 2
    for (int k = 0; k < 100; ++k) {
      float4 w0 = W2v[k * 50 + 2 * q];
      float4 w1 = W2v[k * 50 + 2 * q + 1];
      float4 za = *(const float4*)&zst[k * 84 + n0];
      float4 zb = *(const float4*)&zst[k * 84 + n0 + 4];
#define FMA8(ai, zv) \
  acc0[ai].x += (zv) * w0.x; acc0[ai].y += (zv) * w0.y; \
  acc0[ai].z += (zv) * w0.z; acc0[ai].w += (zv) * w0.w; \
  acc1[ai].x += (zv) * w1.x; acc1[ai].y += (zv) * w1.y; \
  acc1[ai].z += (zv) * w1.z; acc1[ai].w += (zv) * w1.w;
      FMA8(0, za.x) FMA8(1, za.y) FMA8(2, za.z) FMA8(3, za.w)
      FMA8(4, zb.x) FMA8(5, zb.y) FMA8(6, zb.z) FMA8(7, zb.w)
#undef FMA8
    }
    float4 b0v = ((const float4*)b2)[2 * q];
    float4 b1v = ((const float4*)b2)[2 * q + 1];
    float4 run0 = make_float4(0.f, 0.f, 0.f, 0.f);
    float4 run1 = make_float4(0.f, 0.f, 0.f, 0.f);
    int curg = bsm[n0];
#define FLUSH(gv) { \
  int gl = (gv) - gmin; \
  if (gl < 6) { \
    float* pr = &part[gl * 200 + 8 * q]; \
    atomicAdd(&pr[0], run0.x); atomicAdd(&pr[1], run0.y); \
    atomicAdd(&pr[2], run0.z); atomicAdd(&pr[3], run0.w); \
    atomicAdd(&pr[4], run1.x); atomicAdd(&pr[5], run1.y); \
    atomicAdd(&pr[6], run1.z); atomicAdd(&pr[7], run1.w); \
  } else { \
    float* pr = &pooled2[((size_t)(gv) * NSLOT + slot) * 200 + 8 * q]; \
    atomicAdd(&pr[0], run0.x); atomicAdd(&pr[1], run0.y); \
    atomicAdd(&pr[2], run0.z); atomicAdd(&pr[3], run0.w); \
    atomicAdd(&pr[4], run1.x); atomicAdd(&pr[5], run1.y); \
    atomicAdd(&pr[6], run1.z); atomicAdd(&pr[7], run1.w); \
  } }
#pragma unroll
    for (int i = 0; i < 8; ++i) {
      float4 s0, s1;
      s0.x = silu_f(acc0[i].x + b0v.x); s0.y = silu_f(acc0[i].y + b0v.y);
      s0.z = silu_f(acc0[i].z + b0v.z); s0.w = silu_f(acc0[i].w + b0v.w);
      s1.x = silu_f(acc1[i].x + b1v.x); s1.y = silu_f(acc1[i].y + b1v.y);
      s1.z = silu_f(acc1[i].z + b1v.z); s1.w = silu_f(acc1[i].w + b1v.w);
      int g = bsm[n0 + i];
      if (g != curg) {
        FLUSH(curg)
        run0 = make_float4(0.f, 0.f, 0.f, 0.f);
        run1 = make_float4(0.f, 0.f, 0.f, 0.f);
        curg = g;
      }
      run0.x += s0.x; run0.y += s0.y; run0.z += s0.z; run0.w += s0.w;
      run1.x += s1.x; run1.y += s1.y; run1.z += s1.z; run1.w += s1.w;
    }
    FLUSH(curg)
#undef FLUSH
  }
  __syncthreads();
  if (tid < 200) {
    int nloop = min(ngr, 6);
    for (int g = 0; g < nloop; ++g)
      pooled2[((size_t)(gmin + g) * NSLOT + slot) * 200 + tid] = part[g * 200 + tid];
  }
}

// ---- head: sum 32 slots, mean (count via binary search), 2-layer MLP ----
__global__ void k_final(const float* __restrict__ pooled2, const int* __restrict__ batch,
                        const float* __restrict__ Wl1, const float* __restrict__ bl1,
                        const float* __restrict__ Wl2, const float* __restrict__ bl2,
                        float* __restrict__ out) {
  __shared__ float pm[200];
  __shared__ float hid[100];
  __shared__ int bounds[2];
  int g = blockIdx.x;
  int j = threadIdx.x;
  if (j < 2) {
    int target = g + j;
    int lo = 0, hi = NN;
    while (lo < hi) {
      int mid = (lo + hi) >> 1;
      if (batch[mid] < target) lo = mid + 1; else hi = mid;
    }
    bounds[j] = lo;
  }
  float acc = 0.0f;
  if (j < 200) {
    const float* base = pooled2 + (size_t)g * NSLOT * 200 + j;
    for (int s = 0; s < NSLOT; ++s) acc += base[s * 200];
  }
  __syncthreads();
  int cntg = bounds[1] - bounds[0];
  float inv = 1.0f / (float)((cntg > 0) ? cntg : 1);  // exact div, once per graph
  if (j < 200) pm[j] = acc * inv;
  __syncthreads();
  if (j < 100) {
    float a = bl1[j];
    for (int k = 0; k < 200; ++k) a += pm[k] * Wl1[k * 100 + j];
    a = silu_f(a);
    hid[j] = a * Wl2[j];
  }
  __syncthreads();
  if (j == 0) {
    float sum = bl2[0];
    for (int k = 0; k < 100; ++k) sum += hid[k];
    out[g] = sum;
  }
}

extern "C" void kernel_launch(void* const* d_in, const int* in_sizes, int n_in,
                              void* d_out, int out_size, void* d_ws, size_t ws_size,
                              hipStream_t stream) {
  const float* x   = (const float*)d_in[0];
  const float* ew  = (const float*)d_in[1];
  const float* W1  = (const float*)d_in[2];
  const float* b1  = (const float*)d_in[3];
  const float* W2  = (const float*)d_in[4];
  const float* b2  = (const float*)d_in[5];
  const float* Wl1 = (const float*)d_in[6];
  const float* bl1 = (const float*)d_in[7];
  const float* Wl2 = (const float*)d_in[8];
  const float* bl2 = (const float*)d_in[9];
  const int* ei    = (const int*)d_in[10];
  const int* batch = (const int*)d_in[11];
  const int* rowp = ei;            // edge_index[0] = sources
  const int* colp = ei + NE;       // edge_index[1] = targets
  float* out = (float*)d_out;

  char* w = (char*)d_ws;
  size_t o = 0;
  auto alloc = [&](size_t bytes) {
    char* p = w + o;
    o = (o + bytes + 255) & ~(size_t)255;
    return p;
  };
  int*    cur     = (int*)alloc((size_t)NN * 4);
  float4* y4      = (float4*)alloc((size_t)NN * 16);
  float4* a1d     = (float4*)alloc((size_t)NN * 16);
  float*  pooled2 = (float*)alloc((size_t)NG * NSLOT * 200 * 4);  // 1.6 MB
  float*  a2      = (float*)alloc((size_t)NN * 100 * 4);
  int2*   buck    = (int2*)alloc((size_t)NN * CAP * 8);           // 51.2 MB
  int2*   sorted  = (int2*)alloc((size_t)NBUCK * BCAP * 8);       // 14.4 MB
  int*    gcnt    = (int*)alloc((size_t)NBUCK * 16 * 4);          // line-padded

  hipMemsetAsync(gcnt, 0, (size_t)NBUCK * 16 * 4, stream);

  k_scatter<<<NBLK, 512, 0, stream>>>(rowp, colp, ew, gcnt, sorted, pooled2);
  k_group<<<NBUCK, 512, 0, stream>>>(gcnt, sorted, cur, buck, x, y4);
  k_agg1<<<NN / 16, 256, 0, stream>>>(cur, buck, y4, a1d);
  k_agg2r<<<(NN + 3) / 4, 256, 0, stream>>>(a1d, cur, buck, W1, b1, a2);
  k_h2pool<<<NN / NPB, 256, 0, stream>>>(a2, W2, b2, batch, pooled2);
  k_final<<<NG, 256, 0, stream>>>(pooled2, batch, Wl1, bl1, Wl2, bl2, out);
}